// Round 1
// baseline (899.306 us; speedup 1.0000x reference)
//
#include <hip/hip_runtime.h>

// ---------------------------------------------------------------------------
// 2-layer GCN:  out = Ahat * (relu(Ahat * X * W1 + b1)) * W2 + b2
// Ahat = D^-1/2 (A + I) D^-1/2, deg computed with self-loops.
//
// Plan per call (all on `stream`, graph-capture safe):
//   1. cnt[dst]++ histogram (int atomics)
//   2. dinv[i] = rsqrt(cnt[i]+1)
//   3. exclusive scan -> row_ptr, cursor (single 1024-thread block)
//   4. CSR fill: csr_src[atomicAdd(cursor[dst])] = src
//   5. GEMM  h   = X @ W1          (buf1)
//   6. AGG   h1  = relu(Ahat h + b1)  -> d_out (temp)
//   7. GEMM  h2  = h1 @ W2         (buf1)
//   8. AGG   out = Ahat h2 + b2    -> d_out
// ---------------------------------------------------------------------------

__global__ __launch_bounds__(256) void k_count(const int* __restrict__ dst,
                                               int* __restrict__ cnt, int E) {
  int e = blockIdx.x * blockDim.x + threadIdx.x;
  if (e < E) atomicAdd(&cnt[dst[e]], 1);
}

__global__ __launch_bounds__(256) void k_dinv(const int* __restrict__ cnt,
                                              float* __restrict__ dinv, int n) {
  int i = blockIdx.x * blockDim.x + threadIdx.x;
  if (i < n) dinv[i] = rsqrtf((float)cnt[i] + 1.0f);  // +1 = self-loop
}

// Single-block exclusive scan over n counts -> row_ptr[0..n], cursor copy.
__global__ __launch_bounds__(1024) void k_scan(const int* __restrict__ cnt,
                                               int* __restrict__ row_ptr,
                                               int* __restrict__ cursor, int n) {
  __shared__ int sums[1024];
  int t = threadIdx.x;
  int chunk = (n + 1023) >> 10;
  int beg = t * chunk;
  int end = min(beg + chunk, n);
  int s = 0;
  for (int i = beg; i < end; ++i) s += cnt[i];
  sums[t] = s;
  __syncthreads();
  for (int off = 1; off < 1024; off <<= 1) {
    int v = 0;
    if (t >= off) v = sums[t - off];
    __syncthreads();
    if (t >= off) sums[t] += v;
    __syncthreads();
  }
  int run = (t == 0) ? 0 : sums[t - 1];
  for (int i = beg; i < end; ++i) {
    row_ptr[i] = run;
    cursor[i]  = run;
    run += cnt[i];
  }
  if (t == 0) row_ptr[n] = sums[1023];
}

__global__ __launch_bounds__(256) void k_fill(const int* __restrict__ src,
                                              const int* __restrict__ dst,
                                              int* __restrict__ cursor,
                                              int* __restrict__ csr_src, int E) {
  int e = blockIdx.x * blockDim.x + threadIdx.x;
  if (e < E) {
    int d = dst[e];
    int pos = atomicAdd(&cursor[d], 1);
    csr_src[pos] = src[e];
  }
}

// H[n,128] = X[n,128] @ W[128,128]. W + 32-row X tile in LDS, 4x4 reg blocking.
__global__ __launch_bounds__(256) void k_gemm128(const float* __restrict__ X,
                                                 const float* __restrict__ W,
                                                 float* __restrict__ H, int n) {
  __shared__ float Ws[128 * 128];
  __shared__ float Xs[32][128];
  int t = threadIdx.x;
  for (int i = t * 4; i < 128 * 128; i += 256 * 4)
    *(float4*)&Ws[i] = *(const float4*)&W[i];
  int row0 = blockIdx.x * 32;
  for (int i = t * 4; i < 32 * 128; i += 256 * 4) {
    int r = i >> 7, c = i & 127;
    int row = row0 + r;
    float4 v = make_float4(0.f, 0.f, 0.f, 0.f);
    if (row < n) v = *(const float4*)&X[(size_t)row * 128 + c];
    *(float4*)&Xs[r][c] = v;
  }
  __syncthreads();

  int cg = t & 31;   // cols 4*cg .. 4*cg+3
  int rg = t >> 5;   // rows 4*rg .. 4*rg+3
  float acc[4][4] = {};
#pragma unroll 4
  for (int k = 0; k < 128; ++k) {
    float4 w = *(float4*)&Ws[k * 128 + cg * 4];
#pragma unroll
    for (int r = 0; r < 4; ++r) {
      float xv = Xs[rg * 4 + r][k];
      acc[r][0] = fmaf(xv, w.x, acc[r][0]);
      acc[r][1] = fmaf(xv, w.y, acc[r][1]);
      acc[r][2] = fmaf(xv, w.z, acc[r][2]);
      acc[r][3] = fmaf(xv, w.w, acc[r][3]);
    }
  }
#pragma unroll
  for (int r = 0; r < 4; ++r) {
    int row = row0 + rg * 4 + r;
    if (row < n)
      *(float4*)&H[(size_t)row * 128 + cg * 4] =
          make_float4(acc[r][0], acc[r][1], acc[r][2], acc[r][3]);
  }
}

// Pull aggregation: one wave (64 lanes) per node, float2 per lane = 128 cols.
// OUT[i] = sum_{e: dst==i} dinv[i]*dinv[src]*H[src] + dinv[i]^2*H[i] + bias
__global__ __launch_bounds__(256) void k_aggregate(
    const float* __restrict__ H, const int* __restrict__ csr_src,
    const int* __restrict__ row_ptr, const float* __restrict__ dinv,
    const float* __restrict__ bias, float* __restrict__ OUT, int n, int do_relu) {
  int gid = blockIdx.x * blockDim.x + threadIdx.x;
  int node = gid >> 6;
  int lane = threadIdx.x & 63;
  if (node >= n) return;

  float di = dinv[node];
  int beg = row_ptr[node], end = row_ptr[node + 1];

  float2 hv = *(const float2*)(H + (size_t)node * 128 + lane * 2);
  float w0 = di * di;
  float ax = w0 * hv.x, ay = w0 * hv.y;

  for (int e = beg; e < end; ++e) {
    int s = csr_src[e];
    float w = di * dinv[s];
    float2 h = *(const float2*)(H + (size_t)s * 128 + lane * 2);
    ax = fmaf(w, h.x, ax);
    ay = fmaf(w, h.y, ay);
  }

  float2 b = *(const float2*)(bias + lane * 2);
  ax += b.x;
  ay += b.y;
  if (do_relu) {
    ax = fmaxf(ax, 0.f);
    ay = fmaxf(ay, 0.f);
  }
  *(float2*)(OUT + (size_t)node * 128 + lane * 2) = make_float2(ax, ay);
}

extern "C" void kernel_launch(void* const* d_in, const int* in_sizes, int n_in,
                              void* d_out, int out_size, void* d_ws, size_t ws_size,
                              hipStream_t stream) {
  const float* x  = (const float*)d_in[0];
  const int* eidx = (const int*)d_in[1];
  const float* W1 = (const float*)d_in[2];
  const float* b1 = (const float*)d_in[3];
  const float* W2 = (const float*)d_in[4];
  const float* b2 = (const float*)d_in[5];
  float* out = (float*)d_out;

  const int N = in_sizes[0] / 128;
  const int E = in_sizes[1] / 2;
  const int* src = eidx;
  const int* dst = eidx + E;

  char* w = (char*)d_ws;
  float* buf1   = (float*)w; w += (size_t)N * 128 * 4;  // 51.2 MB (16B aligned)
  int* csr_src  = (int*)w;   w += (size_t)E * 4;        // 6.4 MB
  int* row_ptr  = (int*)w;   w += (size_t)(N + 1) * 4;
  int* cursor   = (int*)w;   w += (size_t)N * 4;
  int* cnt      = (int*)w;   w += (size_t)N * 4;
  float* dinv   = (float*)w; w += (size_t)N * 4;

  hipMemsetAsync(cnt, 0, (size_t)N * 4, stream);
  k_count<<<(E + 255) / 256, 256, 0, stream>>>(dst, cnt, E);
  k_dinv<<<(N + 255) / 256, 256, 0, stream>>>(cnt, dinv, N);
  k_scan<<<1, 1024, 0, stream>>>(cnt, row_ptr, cursor, N);
  k_fill<<<(E + 255) / 256, 256, 0, stream>>>(src, dst, cursor, csr_src, E);

  // layer 1: buf1 = X @ W1 ; d_out = relu(Ahat buf1 + b1)
  k_gemm128<<<(N + 31) / 32, 256, 0, stream>>>(x, W1, buf1, N);
  k_aggregate<<<(N * 64 + 255) / 256, 256, 0, stream>>>(buf1, csr_src, row_ptr,
                                                        dinv, b1, out, N, 1);
  // layer 2: buf1 = h1 @ W2 ; d_out = Ahat buf1 + b2
  k_gemm128<<<(N + 31) / 32, 256, 0, stream>>>(out, W2, buf1, N);
  k_aggregate<<<(N * 64 + 255) / 256, 256, 0, stream>>>(buf1, csr_src, row_ptr,
                                                        dinv, b2, out, N, 0);
}

// Round 2
// 674.636 us; speedup vs baseline: 1.3330x; 1.3330x over previous
//
#include <hip/hip_runtime.h>

// ---------------------------------------------------------------------------
// 2-layer GCN:  out = Ahat * (relu(Ahat * X * W1 + b1)) * W2 + b2
// Ahat = D^-1/2 (A + I) D^-1/2, deg computed with self-loops.
//
// Per call (all on `stream`, graph-capture safe):
//   1. cnt[dst]++ histogram (int atomics)
//   2. dinv[i] = rsqrt(cnt[i]+1)
//   3. hierarchical exclusive scan -> row_ptr, cursor  (3 small kernels;
//      the old single-block scan was 233 us latency-bound on one CU)
//   4. CSR fill: csr_src[atomicAdd(cursor[dst])] = src
//   5. GEMM  h   = X @ W1          (buf1)
//   6. AGG   h1  = relu(Ahat h + b1)  -> d_out (temp)
//   7. GEMM  h2  = h1 @ W2         (buf1)
//   8. AGG   out = Ahat h2 + b2    -> d_out
// ---------------------------------------------------------------------------

__global__ __launch_bounds__(256) void k_count(const int* __restrict__ dst,
                                               int* __restrict__ cnt, int E) {
  int e = blockIdx.x * blockDim.x + threadIdx.x;
  if (e < E) atomicAdd(&cnt[dst[e]], 1);
}

__global__ __launch_bounds__(256) void k_dinv(const int* __restrict__ cnt,
                                              float* __restrict__ dinv, int n) {
  int i = blockIdx.x * blockDim.x + threadIdx.x;
  if (i < n) dinv[i] = rsqrtf((float)cnt[i] + 1.0f);  // +1 = self-loop
}

// --- hierarchical scan: 1024 elements per block ----------------------------

__global__ __launch_bounds__(256) void k_blocksum(const int* __restrict__ cnt,
                                                  int* __restrict__ bsum, int n) {
  int base = blockIdx.x * 1024 + threadIdx.x * 4;
  int s = 0;
  if (base + 3 < n) {
    int4 q = *(const int4*)&cnt[base];
    s = q.x + q.y + q.z + q.w;
  } else {
    for (int i = 0; i < 4; ++i)
      if (base + i < n) s += cnt[base + i];
  }
#pragma unroll
  for (int off = 1; off < 64; off <<= 1) s += __shfl_xor(s, off);
  __shared__ int ws[4];
  int lane = threadIdx.x & 63, wid = threadIdx.x >> 6;
  if (lane == 0) ws[wid] = s;
  __syncthreads();
  if (threadIdx.x == 0) bsum[blockIdx.x] = ws[0] + ws[1] + ws[2] + ws[3];
}

// single small block: exclusive scan of nb (<1024) block sums, total -> row_ptr[n]
__global__ __launch_bounds__(1024) void k_scan_bsum(int* __restrict__ bsum, int nb,
                                                    int* __restrict__ row_ptr, int n) {
  __shared__ int s[1024];
  int t = threadIdx.x;
  s[t] = (t < nb) ? bsum[t] : 0;
  __syncthreads();
  for (int off = 1; off < 1024; off <<= 1) {
    int u = 0;
    if (t >= off) u = s[t - off];
    __syncthreads();
    if (t >= off) s[t] += u;
    __syncthreads();
  }
  if (t < nb) bsum[t] = (t == 0) ? 0 : s[t - 1];
  if (t == 0) row_ptr[n] = s[nb - 1];
}

__global__ __launch_bounds__(256) void k_scan_write(const int* __restrict__ cnt,
                                                    const int* __restrict__ bsum,
                                                    int* __restrict__ row_ptr,
                                                    int* __restrict__ cursor, int n) {
  int t = threadIdx.x;
  int lane = t & 63, wid = t >> 6;
  int base = blockIdx.x * 1024 + t * 4;
  int v[4];
  if (base + 3 < n) {
    int4 q = *(const int4*)&cnt[base];
    v[0] = q.x; v[1] = q.y; v[2] = q.z; v[3] = q.w;
  } else {
    for (int i = 0; i < 4; ++i) v[i] = (base + i < n) ? cnt[base + i] : 0;
  }
  int tsum = v[0] + v[1] + v[2] + v[3];
  int inc = tsum;
#pragma unroll
  for (int off = 1; off < 64; off <<= 1) {
    int u = __shfl_up(inc, off);
    if (lane >= off) inc += u;
  }
  __shared__ int wtot[4];
  if (lane == 63) wtot[wid] = inc;
  __syncthreads();
  int woff = 0;
  for (int i = 0; i < wid; ++i) woff += wtot[i];
  int run = bsum[blockIdx.x] + woff + (inc - tsum);
  for (int i = 0; i < 4; ++i) {
    int idx = base + i;
    if (idx < n) { row_ptr[idx] = run; cursor[idx] = run; }
    run += v[i];
  }
}

__global__ __launch_bounds__(256) void k_fill(const int* __restrict__ src,
                                              const int* __restrict__ dst,
                                              int* __restrict__ cursor,
                                              int* __restrict__ csr_src, int E) {
  int e = blockIdx.x * blockDim.x + threadIdx.x;
  if (e < E) {
    int d = dst[e];
    int pos = atomicAdd(&cursor[d], 1);
    csr_src[pos] = src[e];
  }
}

// H[n,128] = X[n,128] @ W[128,128]. W + 32-row X tile in LDS, 4x4 reg blocking.
__global__ __launch_bounds__(256) void k_gemm128(const float* __restrict__ X,
                                                 const float* __restrict__ W,
                                                 float* __restrict__ H, int n) {
  __shared__ float Ws[128 * 128];
  __shared__ float Xs[32][128];
  int t = threadIdx.x;
  for (int i = t * 4; i < 128 * 128; i += 256 * 4)
    *(float4*)&Ws[i] = *(const float4*)&W[i];
  int row0 = blockIdx.x * 32;
  for (int i = t * 4; i < 32 * 128; i += 256 * 4) {
    int r = i >> 7, c = i & 127;
    int row = row0 + r;
    float4 v = make_float4(0.f, 0.f, 0.f, 0.f);
    if (row < n) v = *(const float4*)&X[(size_t)row * 128 + c];
    *(float4*)&Xs[r][c] = v;
  }
  __syncthreads();

  int cg = t & 31;   // cols 4*cg .. 4*cg+3
  int rg = t >> 5;   // rows 4*rg .. 4*rg+3
  float acc[4][4] = {};
#pragma unroll 4
  for (int k = 0; k < 128; ++k) {
    float4 w = *(float4*)&Ws[k * 128 + cg * 4];
#pragma unroll
    for (int r = 0; r < 4; ++r) {
      float xv = Xs[rg * 4 + r][k];
      acc[r][0] = fmaf(xv, w.x, acc[r][0]);
      acc[r][1] = fmaf(xv, w.y, acc[r][1]);
      acc[r][2] = fmaf(xv, w.z, acc[r][2]);
      acc[r][3] = fmaf(xv, w.w, acc[r][3]);
    }
  }
#pragma unroll
  for (int r = 0; r < 4; ++r) {
    int row = row0 + rg * 4 + r;
    if (row < n)
      *(float4*)&H[(size_t)row * 128 + cg * 4] =
          make_float4(acc[r][0], acc[r][1], acc[r][2], acc[r][3]);
  }
}

// Pull aggregation: one wave (64 lanes) per node, float2 per lane = 128 cols.
// OUT[i] = sum_{e: dst==i} dinv[i]*dinv[src]*H[src] + dinv[i]^2*H[i] + bias
__global__ __launch_bounds__(256) void k_aggregate(
    const float* __restrict__ H, const int* __restrict__ csr_src,
    const int* __restrict__ row_ptr, const float* __restrict__ dinv,
    const float* __restrict__ bias, float* __restrict__ OUT, int n, int do_relu) {
  int gid = blockIdx.x * blockDim.x + threadIdx.x;
  int node = gid >> 6;
  int lane = threadIdx.x & 63;
  if (node >= n) return;

  float di = dinv[node];
  int beg = row_ptr[node], end = row_ptr[node + 1];

  float2 hv = *(const float2*)(H + (size_t)node * 128 + lane * 2);
  float w0 = di * di;
  float ax = w0 * hv.x, ay = w0 * hv.y;

  for (int e = beg; e < end; ++e) {
    int s = csr_src[e];
    float w = di * dinv[s];
    float2 h = *(const float2*)(H + (size_t)s * 128 + lane * 2);
    ax = fmaf(w, h.x, ax);
    ay = fmaf(w, h.y, ay);
  }

  float2 b = *(const float2*)(bias + lane * 2);
  ax += b.x;
  ay += b.y;
  if (do_relu) {
    ax = fmaxf(ax, 0.f);
    ay = fmaxf(ay, 0.f);
  }
  *(float2*)(OUT + (size_t)node * 128 + lane * 2) = make_float2(ax, ay);
}

extern "C" void kernel_launch(void* const* d_in, const int* in_sizes, int n_in,
                              void* d_out, int out_size, void* d_ws, size_t ws_size,
                              hipStream_t stream) {
  const float* x  = (const float*)d_in[0];
  const int* eidx = (const int*)d_in[1];
  const float* W1 = (const float*)d_in[2];
  const float* b1 = (const float*)d_in[3];
  const float* W2 = (const float*)d_in[4];
  const float* b2 = (const float*)d_in[5];
  float* out = (float*)d_out;

  const int N = in_sizes[0] / 128;
  const int E = in_sizes[1] / 2;
  const int* src = eidx;
  const int* dst = eidx + E;
  const int NB = (N + 1023) / 1024;  // scan blocks (1024 elems each)

  auto align16 = [](size_t v) { return (v + 15) & ~(size_t)15; };
  char* w = (char*)d_ws;
  float* buf1   = (float*)w; w += align16((size_t)N * 128 * 4);  // 51.2 MB
  int* csr_src  = (int*)w;   w += align16((size_t)E * 4);        // 6.4 MB
  int* row_ptr  = (int*)w;   w += align16((size_t)(N + 1) * 4);
  int* cursor   = (int*)w;   w += align16((size_t)N * 4);
  int* cnt      = (int*)w;   w += align16((size_t)N * 4);
  float* dinv   = (float*)w; w += align16((size_t)N * 4);
  int* bsum     = (int*)w;   w += align16((size_t)NB * 4);

  hipMemsetAsync(cnt, 0, (size_t)N * 4, stream);
  k_count<<<(E + 255) / 256, 256, 0, stream>>>(dst, cnt, E);
  k_dinv<<<(N + 255) / 256, 256, 0, stream>>>(cnt, dinv, N);
  k_blocksum<<<NB, 256, 0, stream>>>(cnt, bsum, N);
  k_scan_bsum<<<1, 1024, 0, stream>>>(bsum, NB, row_ptr, N);
  k_scan_write<<<NB, 256, 0, stream>>>(cnt, bsum, row_ptr, cursor, N);
  k_fill<<<(E + 255) / 256, 256, 0, stream>>>(src, dst, cursor, csr_src, E);

  // layer 1: buf1 = X @ W1 ; d_out = relu(Ahat buf1 + b1)
  k_gemm128<<<(N + 31) / 32, 256, 0, stream>>>(x, W1, buf1, N);
  k_aggregate<<<(N * 64 + 255) / 256, 256, 0, stream>>>(buf1, csr_src, row_ptr,
                                                        dinv, b1, out, N, 1);
  // layer 2: buf1 = h1 @ W2 ; d_out = Ahat buf1 + b2
  k_gemm128<<<(N + 31) / 32, 256, 0, stream>>>(out, W2, buf1, N);
  k_aggregate<<<(N * 64 + 255) / 256, 256, 0, stream>>>(buf1, csr_src, row_ptr,
                                                        dinv, b2, out, N, 0);
}

// Round 3
// 448.719 us; speedup vs baseline: 2.0042x; 1.5035x over previous
//
#include <hip/hip_runtime.h>

// ---------------------------------------------------------------------------
// 2-layer GCN:  out = Ahat * (relu(Ahat * X * W1 + b1)) * W2 + b2
// Ahat = D^-1/2 (A + I) D^-1/2, deg computed with self-loops.
//
// Round-3 structure: h buffers stored in bf16 (halves the random-gather
// L2-miss traffic that bounds k_aggregate), GEMMs via bf16 MFMA
// (mfma_f32_16x16x32_bf16) with fp32 accumulate.
// ---------------------------------------------------------------------------

typedef __attribute__((ext_vector_type(8))) short bf16x8;
typedef __attribute__((ext_vector_type(4))) float f32x4;
typedef unsigned int uint;
typedef unsigned short ushort;

__device__ __forceinline__ ushort f2bf(float f) {  // RNE f32 -> bf16
  union { float f; uint u; } c; c.f = f;
  uint u = c.u;
  uint r = u + 0x7fffu + ((u >> 16) & 1u);
  return (ushort)(r >> 16);
}
__device__ __forceinline__ float bf_lo(uint u) {  // low bf16 of packed pair
  union { uint i; float f; } c; c.i = u << 16; return c.f;
}
__device__ __forceinline__ float bf_hi(uint u) {  // high bf16
  union { uint i; float f; } c; c.i = u & 0xffff0000u; return c.f;
}

// --------------------------- CSR build -------------------------------------

__global__ __launch_bounds__(256) void k_count(const int* __restrict__ dst,
                                               int* __restrict__ cnt, int E) {
  int e = blockIdx.x * blockDim.x + threadIdx.x;
  if (e < E) atomicAdd(&cnt[dst[e]], 1);
}

__global__ __launch_bounds__(256) void k_dinv(const int* __restrict__ cnt,
                                              float* __restrict__ dinv, int n) {
  int i = blockIdx.x * blockDim.x + threadIdx.x;
  if (i < n) dinv[i] = rsqrtf((float)cnt[i] + 1.0f);  // +1 = self-loop
}

__global__ __launch_bounds__(256) void k_blocksum(const int* __restrict__ cnt,
                                                  int* __restrict__ bsum, int n) {
  int base = blockIdx.x * 1024 + threadIdx.x * 4;
  int s = 0;
  if (base + 3 < n) {
    int4 q = *(const int4*)&cnt[base];
    s = q.x + q.y + q.z + q.w;
  } else {
    for (int i = 0; i < 4; ++i)
      if (base + i < n) s += cnt[base + i];
  }
#pragma unroll
  for (int off = 1; off < 64; off <<= 1) s += __shfl_xor(s, off);
  __shared__ int ws[4];
  int lane = threadIdx.x & 63, wid = threadIdx.x >> 6;
  if (lane == 0) ws[wid] = s;
  __syncthreads();
  if (threadIdx.x == 0) bsum[blockIdx.x] = ws[0] + ws[1] + ws[2] + ws[3];
}

__global__ __launch_bounds__(1024) void k_scan_bsum(int* __restrict__ bsum, int nb,
                                                    int* __restrict__ row_ptr, int n) {
  __shared__ int s[1024];
  int t = threadIdx.x;
  s[t] = (t < nb) ? bsum[t] : 0;
  __syncthreads();
  for (int off = 1; off < 1024; off <<= 1) {
    int u = 0;
    if (t >= off) u = s[t - off];
    __syncthreads();
    if (t >= off) s[t] += u;
    __syncthreads();
  }
  if (t < nb) bsum[t] = (t == 0) ? 0 : s[t - 1];
  if (t == 0) row_ptr[n] = s[nb - 1];
}

__global__ __launch_bounds__(256) void k_scan_write(const int* __restrict__ cnt,
                                                    const int* __restrict__ bsum,
                                                    int* __restrict__ row_ptr,
                                                    int* __restrict__ cursor, int n) {
  int t = threadIdx.x;
  int lane = t & 63, wid = t >> 6;
  int base = blockIdx.x * 1024 + t * 4;
  int v[4];
  if (base + 3 < n) {
    int4 q = *(const int4*)&cnt[base];
    v[0] = q.x; v[1] = q.y; v[2] = q.z; v[3] = q.w;
  } else {
    for (int i = 0; i < 4; ++i) v[i] = (base + i < n) ? cnt[base + i] : 0;
  }
  int tsum = v[0] + v[1] + v[2] + v[3];
  int inc = tsum;
#pragma unroll
  for (int off = 1; off < 64; off <<= 1) {
    int u = __shfl_up(inc, off);
    if (lane >= off) inc += u;
  }
  __shared__ int wtot[4];
  if (lane == 63) wtot[wid] = inc;
  __syncthreads();
  int woff = 0;
  for (int i = 0; i < wid; ++i) woff += wtot[i];
  int run = bsum[blockIdx.x] + woff + (inc - tsum);
  for (int i = 0; i < 4; ++i) {
    int idx = base + i;
    if (idx < n) { row_ptr[idx] = run; cursor[idx] = run; }
    run += v[i];
  }
}

__global__ __launch_bounds__(256) void k_fill(const int* __restrict__ src,
                                              const int* __restrict__ dst,
                                              int* __restrict__ cursor,
                                              int* __restrict__ csr_src, int E) {
  int e = blockIdx.x * blockDim.x + threadIdx.x;
  if (e < E) {
    int d = dst[e];
    int pos = atomicAdd(&cursor[d], 1);
    csr_src[pos] = src[e];
  }
}

// --------------------------- MFMA GEMM -------------------------------------
// H[n,128](bf16) = A[n,128] @ W[128,128].  A fp32 (layer1) or bf16 (layer2).
// Block: 256 thr = 4 waves, 128 rows. Wave w: rows w*32..w*32+31 (2 row-tiles),
// all 8 col-tiles. K=128 in 4 steps of 32.
// W staged in LDS chunk-major: Bt[chunk=k/8][col][8 elems of k] (bf16, 32KB):
//  - staging: coalesced 4B global reads, ds_write_b128 (8-way bank, one-time)
//  - read: ds_read_b128 at 2-way bank aliasing (free).
// MFMA frag layouts (gfx950, verified m89): A: row=lane&15, k=(lane>>4)*8+j;
// B: col=lane&15, k=(lane>>4)*8+j; D: col=lane&15, row=(lane>>4)*4+reg.

__device__ __forceinline__ bf16x8 pack8(float4 u, float4 v) {
  bf16x8 r;
  r[0] = (short)f2bf(u.x); r[1] = (short)f2bf(u.y);
  r[2] = (short)f2bf(u.z); r[3] = (short)f2bf(u.w);
  r[4] = (short)f2bf(v.x); r[5] = (short)f2bf(v.y);
  r[6] = (short)f2bf(v.z); r[7] = (short)f2bf(v.w);
  return r;
}

template <bool A_IS_F32>
__global__ __launch_bounds__(256) void k_gemm_mfma(const void* __restrict__ A,
                                                   const float* __restrict__ Wf,
                                                   ushort* __restrict__ H, int n) {
  __shared__ __align__(16) ushort Bt[16 * 128 * 8];  // [chunk][col][8]
  int t = threadIdx.x;
  for (int id = t; id < 16 * 128; id += 256) {
    int col = id & 127, ch = id >> 7;
    ushort us[8];
#pragma unroll
    for (int j = 0; j < 8; ++j) us[j] = f2bf(Wf[(ch * 8 + j) * 128 + col]);
    uint4 p;
    p.x = (uint)us[0] | ((uint)us[1] << 16);
    p.y = (uint)us[2] | ((uint)us[3] << 16);
    p.z = (uint)us[4] | ((uint)us[5] << 16);
    p.w = (uint)us[6] | ((uint)us[7] << 16);
    *(uint4*)&Bt[id * 8] = p;
  }
  __syncthreads();

  int wv = t >> 6, lane = t & 63;
  int r16 = lane & 15, kg = lane >> 4;
  int row0 = blockIdx.x * 128 + wv * 32;
  f32x4 acc[2][8] = {};

#pragma unroll
  for (int ks = 0; ks < 4; ++ks) {
    bf16x8 a0, a1;
    if (A_IS_F32) {
      const float* Af = (const float*)A;
      int r = min(row0 + r16, n - 1);
      const float* p = &Af[(size_t)r * 128 + ks * 32 + kg * 8];
      a0 = pack8(*(const float4*)p, *(const float4*)(p + 4));
      r = min(row0 + 16 + r16, n - 1);
      p = &Af[(size_t)r * 128 + ks * 32 + kg * 8];
      a1 = pack8(*(const float4*)p, *(const float4*)(p + 4));
    } else {
      const ushort* Ab = (const ushort*)A;
      int r = min(row0 + r16, n - 1);
      a0 = *(const bf16x8*)&Ab[(size_t)r * 128 + ks * 32 + kg * 8];
      r = min(row0 + 16 + r16, n - 1);
      a1 = *(const bf16x8*)&Ab[(size_t)r * 128 + ks * 32 + kg * 8];
    }
#pragma unroll
    for (int tc = 0; tc < 8; ++tc) {
      bf16x8 b = *(const bf16x8*)&Bt[(((ks * 4 + kg) * 128) + tc * 16 + r16) * 8];
      acc[0][tc] = __builtin_amdgcn_mfma_f32_16x16x32_bf16(a0, b, acc[0][tc], 0, 0, 0);
      acc[1][tc] = __builtin_amdgcn_mfma_f32_16x16x32_bf16(a1, b, acc[1][tc], 0, 0, 0);
    }
  }

#pragma unroll
  for (int rt = 0; rt < 2; ++rt)
#pragma unroll
    for (int tc = 0; tc < 8; ++tc)
#pragma unroll
      for (int rg = 0; rg < 4; ++rg) {
        int row = row0 + rt * 16 + kg * 4 + rg;
        if (row < n) H[(size_t)row * 128 + tc * 16 + r16] = f2bf(acc[rt][tc][rg]);
      }
}

// --------------------------- Aggregation -----------------------------------
// One wave per node; lane owns 2 cols (one packed bf16 pair = 4B -> 256B/row).
// MODE 0: out bf16 with relu (layer 1).  MODE 1: out fp32, no relu (layer 2).

template <int MODE>
__global__ __launch_bounds__(256) void k_aggregate(
    const ushort* __restrict__ H, const int* __restrict__ csr_src,
    const int* __restrict__ row_ptr, const float* __restrict__ dinv,
    const float* __restrict__ bias, ushort* __restrict__ outb,
    float* __restrict__ outf, int n) {
  int node = (blockIdx.x * blockDim.x + threadIdx.x) >> 6;
  int lane = threadIdx.x & 63;
  if (node >= n) return;

  float di = dinv[node];
  int beg = row_ptr[node], end = row_ptr[node + 1];

  uint su = *(const uint*)&H[(size_t)node * 128 + lane * 2];
  float w0 = di * di;
  float ax = w0 * bf_lo(su), ay = w0 * bf_hi(su);

  int e = beg;
  for (; e + 1 < end; e += 2) {
    int s0 = csr_src[e], s1 = csr_src[e + 1];
    float q0 = di * dinv[s0], q1 = di * dinv[s1];
    uint u0 = *(const uint*)&H[(size_t)s0 * 128 + lane * 2];
    uint u1 = *(const uint*)&H[(size_t)s1 * 128 + lane * 2];
    ax = fmaf(q0, bf_lo(u0), ax); ay = fmaf(q0, bf_hi(u0), ay);
    ax = fmaf(q1, bf_lo(u1), ax); ay = fmaf(q1, bf_hi(u1), ay);
  }
  if (e < end) {
    int s0 = csr_src[e];
    float q0 = di * dinv[s0];
    uint u0 = *(const uint*)&H[(size_t)s0 * 128 + lane * 2];
    ax = fmaf(q0, bf_lo(u0), ax); ay = fmaf(q0, bf_hi(u0), ay);
  }

  float2 b = *(const float2*)&bias[lane * 2];
  ax += b.x; ay += b.y;
  if (MODE == 0) {
    ax = fmaxf(ax, 0.f); ay = fmaxf(ay, 0.f);
    uint o = (uint)f2bf(ax) | ((uint)f2bf(ay) << 16);
    *(uint*)&outb[(size_t)node * 128 + lane * 2] = o;
  } else {
    *(float2*)&outf[(size_t)node * 128 + lane * 2] = make_float2(ax, ay);
  }
}

// ---------------------------------------------------------------------------

extern "C" void kernel_launch(void* const* d_in, const int* in_sizes, int n_in,
                              void* d_out, int out_size, void* d_ws, size_t ws_size,
                              hipStream_t stream) {
  const float* x  = (const float*)d_in[0];
  const int* eidx = (const int*)d_in[1];
  const float* W1 = (const float*)d_in[2];
  const float* b1 = (const float*)d_in[3];
  const float* W2 = (const float*)d_in[4];
  const float* b2 = (const float*)d_in[5];
  float* out = (float*)d_out;

  const int N = in_sizes[0] / 128;
  const int E = in_sizes[1] / 2;
  const int* src = eidx;
  const int* dst = eidx + E;
  const int NB = (N + 1023) / 1024;

  auto align16 = [](size_t v) { return (v + 15) & ~(size_t)15; };
  char* w = (char*)d_ws;
  ushort* hb    = (ushort*)w; w += align16((size_t)N * 128 * 2);  // 25.6 MB
  ushort* h1b   = (ushort*)w; w += align16((size_t)N * 128 * 2);  // 25.6 MB
  int* csr_src  = (int*)w;    w += align16((size_t)E * 4);        // 6.4 MB
  int* row_ptr  = (int*)w;    w += align16((size_t)(N + 1) * 4);
  int* cursor   = (int*)w;    w += align16((size_t)N * 4);
  int* cnt      = (int*)w;    w += align16((size_t)N * 4);
  float* dinv   = (float*)w;  w += align16((size_t)N * 4);
  int* bsum     = (int*)w;    w += align16((size_t)NB * 4);

  hipMemsetAsync(cnt, 0, (size_t)N * 4, stream);
  k_count<<<(E + 255) / 256, 256, 0, stream>>>(dst, cnt, E);
  k_dinv<<<(N + 255) / 256, 256, 0, stream>>>(cnt, dinv, N);
  k_blocksum<<<NB, 256, 0, stream>>>(cnt, bsum, N);
  k_scan_bsum<<<1, 1024, 0, stream>>>(bsum, NB, row_ptr, N);
  k_scan_write<<<NB, 256, 0, stream>>>(cnt, bsum, row_ptr, cursor, N);
  k_fill<<<(E + 255) / 256, 256, 0, stream>>>(src, dst, cursor, csr_src, E);

  const int GB = (N + 127) / 128;  // gemm blocks
  // layer 1: hb = bf16(X @ W1); h1b = bf16(relu(Ahat hb + b1))
  k_gemm_mfma<true><<<GB, 256, 0, stream>>>(x, W1, hb, N);
  k_aggregate<0><<<(N * 64 + 255) / 256, 256, 0, stream>>>(
      hb, csr_src, row_ptr, dinv, b1, h1b, nullptr, N);
  // layer 2: hb = bf16(h1b @ W2); out = Ahat hb + b2 (fp32)
  k_gemm_mfma<false><<<GB, 256, 0, stream>>>(h1b, W2, hb, N);
  k_aggregate<1><<<(N * 64 + 255) / 256, 256, 0, stream>>>(
      hb, csr_src, row_ptr, dinv, b2, nullptr, out, N);
}

// Round 4
// 312.843 us; speedup vs baseline: 2.8746x; 1.4343x over previous
//
#include <hip/hip_runtime.h>

// ---------------------------------------------------------------------------
// 2-layer GCN:  out = Ahat * (relu(Ahat * X * W1 + b1)) * W2 + b2
// Ahat = D^-1/2 (A + I) D^-1/2, deg computed with self-loops.
//
// Round-4: bucketed counting-sort CSR build (4 kernels, locality-friendly)
// replaces the scattered-atomic count/scan/fill (was 131us k_fill alone:
// 105 MB of partial-line HBM writes for a 6.4 MB array). h in bf16; GEMMs
// via mfma_f32_16x16x32_bf16.
// ---------------------------------------------------------------------------

typedef __attribute__((ext_vector_type(8))) short bf16x8;
typedef __attribute__((ext_vector_type(4))) float f32x4;
typedef unsigned int uint;
typedef unsigned short ushort;

#define BKT_SHIFT 9
#define BKT_NODES 512   // nodes per bucket; NBK = ceil(N/512) <= 1024

__device__ __forceinline__ ushort f2bf(float f) {  // RNE f32 -> bf16
  union { float f; uint u; } c; c.f = f;
  uint u = c.u;
  uint r = u + 0x7fffu + ((u >> 16) & 1u);
  return (ushort)(r >> 16);
}
__device__ __forceinline__ float bf_lo(uint u) {
  union { uint i; float f; } c; c.i = u << 16; return c.f;
}
__device__ __forceinline__ float bf_hi(uint u) {
  union { uint i; float f; } c; c.i = u & 0xffff0000u; return c.f;
}

// --------------------------- CSR build (bucketed) --------------------------

// P1: global bucket histogram via per-block LDS histograms.
__global__ __launch_bounds__(256) void k_bktcnt(const int* __restrict__ dst,
                                                int* __restrict__ bcnt_g,
                                                int E, int nbk) {
  __shared__ int h[1024];
  int t = threadIdx.x;
  for (int i = t; i < nbk; i += 256) h[i] = 0;
  __syncthreads();
  int chunk = (E + gridDim.x - 1) / gridDim.x;
  int beg = blockIdx.x * chunk, end = min(E, beg + chunk);
  for (int e = beg + t; e < end; e += 256)
    atomicAdd(&h[dst[e] >> BKT_SHIFT], 1);
  __syncthreads();
  for (int i = t; i < nbk; i += 256)
    if (h[i]) atomicAdd(&bcnt_g[i], h[i]);
}

// P2: exclusive scan of bucket counts (nbk <= 1024) -> bbase, bcur.
__global__ __launch_bounds__(1024) void k_bktscan(const int* __restrict__ bcnt_g,
                                                  int* __restrict__ bbase,
                                                  int* __restrict__ bcur,
                                                  int nbk, int E,
                                                  int* __restrict__ row_ptr, int N) {
  __shared__ int s[1024];
  int t = threadIdx.x;
  s[t] = (t < nbk) ? bcnt_g[t] : 0;
  __syncthreads();
  for (int off = 1; off < 1024; off <<= 1) {
    int u = 0;
    if (t >= off) u = s[t - off];
    __syncthreads();
    if (t >= off) s[t] += u;
    __syncthreads();
  }
  if (t < nbk) {
    int ex = (t == 0) ? 0 : s[t - 1];
    bbase[t] = ex;
    bcur[t] = ex;
  }
  if (t == 0) { bbase[nbk] = E; row_ptr[N] = E; }
}

// P3: scatter edges into bucket-contiguous runs. One packed uint per edge:
// (src << 9) | (dst & 511). Per-block reservation = 1 atomic per bucket.
__global__ __launch_bounds__(256) void k_bktscatter(const int* __restrict__ src,
                                                    const int* __restrict__ dst,
                                                    int* __restrict__ bcur,
                                                    uint* __restrict__ ebuf,
                                                    int E, int nbk) {
  __shared__ int h[1024];
  __shared__ int rbase[1024];
  int t = threadIdx.x;
  for (int i = t; i < nbk; i += 256) h[i] = 0;
  __syncthreads();
  int chunk = (E + gridDim.x - 1) / gridDim.x;
  int beg = blockIdx.x * chunk, end = min(E, beg + chunk);
  for (int e = beg + t; e < end; e += 256)
    atomicAdd(&h[dst[e] >> BKT_SHIFT], 1);
  __syncthreads();
  for (int i = t; i < nbk; i += 256) {
    int c = h[i];
    rbase[i] = c ? atomicAdd(&bcur[i], c) : 0;
    h[i] = 0;  // reuse as per-block cursor
  }
  __syncthreads();
  for (int e = beg + t; e < end; e += 256) {
    int d = dst[e];
    int b = d >> BKT_SHIFT;
    int pos = rbase[b] + atomicAdd(&h[b], 1);
    ebuf[pos] = ((uint)src[e] << BKT_SHIFT) | (uint)(d & (BKT_NODES - 1));
  }
}

// P4: one block per bucket: LDS node-histogram -> LDS scan -> row_ptr/dinv
// (coalesced) -> csr_src scatter confined to the bucket's contiguous region.
__global__ __launch_bounds__(256) void k_bktcsr(const uint* __restrict__ ebuf,
                                                const int* __restrict__ bbase,
                                                int* __restrict__ row_ptr,
                                                float* __restrict__ dinv,
                                                int* __restrict__ csr_src, int N) {
  __shared__ int ncnt[BKT_NODES];
  __shared__ int nscan[BKT_NODES];
  __shared__ int ncur[BKT_NODES];
  __shared__ int wtot[4];
  int t = threadIdx.x;
  int b = blockIdx.x;
  int node0 = b << BKT_SHIFT;
  int ebase = bbase[b];
  int eend = bbase[b + 1];
  ncnt[t] = 0; ncnt[t + 256] = 0;
  ncur[t] = 0; ncur[t + 256] = 0;
  __syncthreads();
  for (int e = ebase + t; e < eend; e += 256)
    atomicAdd(&ncnt[ebuf[e] & (BKT_NODES - 1)], 1);
  __syncthreads();
  // exclusive scan of 512 counts: 2 elems/thread + wave scan + wave offsets
  int v0 = ncnt[2 * t], v1 = ncnt[2 * t + 1];
  int s = v0 + v1;
  int lane = t & 63, wv = t >> 6;
  int inc = s;
#pragma unroll
  for (int off = 1; off < 64; off <<= 1) {
    int u = __shfl_up(inc, off);
    if (lane >= off) inc += u;
  }
  if (lane == 63) wtot[wv] = inc;
  __syncthreads();
  int woff = 0;
  for (int i = 0; i < wv; ++i) woff += wtot[i];
  int ex = woff + inc - s;
  nscan[2 * t] = ex;
  nscan[2 * t + 1] = ex + v0;
  int n0 = node0 + 2 * t;
  if (n0 < N) {
    row_ptr[n0] = ebase + ex;
    dinv[n0] = rsqrtf((float)v0 + 1.0f);
  }
  if (n0 + 1 < N) {
    row_ptr[n0 + 1] = ebase + ex + v0;
    dinv[n0 + 1] = rsqrtf((float)v1 + 1.0f);
  }
  __syncthreads();
  for (int e = ebase + t; e < eend; e += 256) {
    uint u = ebuf[e];
    int l = u & (BKT_NODES - 1);
    int pos = ebase + nscan[l] + atomicAdd(&ncur[l], 1);
    csr_src[pos] = (int)(u >> BKT_SHIFT);
  }
}

// --------------------------- MFMA GEMM -------------------------------------
// H[n,128](bf16) = A[n,128] @ W[128,128].  A fp32 (layer1) or bf16 (layer2).
// W staged in LDS chunk-major Bt[k/8][col][8]; frag layouts per m89.

__device__ __forceinline__ bf16x8 pack8(float4 u, float4 v) {
  bf16x8 r;
  r[0] = (short)f2bf(u.x); r[1] = (short)f2bf(u.y);
  r[2] = (short)f2bf(u.z); r[3] = (short)f2bf(u.w);
  r[4] = (short)f2bf(v.x); r[5] = (short)f2bf(v.y);
  r[6] = (short)f2bf(v.z); r[7] = (short)f2bf(v.w);
  return r;
}

template <bool A_IS_F32>
__global__ __launch_bounds__(256) void k_gemm_mfma(const void* __restrict__ A,
                                                   const float* __restrict__ Wf,
                                                   ushort* __restrict__ H, int n) {
  __shared__ __align__(16) ushort Bt[16 * 128 * 8];  // [chunk][col][8]
  int t = threadIdx.x;
  for (int id = t; id < 16 * 128; id += 256) {
    int col = id & 127, ch = id >> 7;
    ushort us[8];
#pragma unroll
    for (int j = 0; j < 8; ++j) us[j] = f2bf(Wf[(ch * 8 + j) * 128 + col]);
    uint4 p;
    p.x = (uint)us[0] | ((uint)us[1] << 16);
    p.y = (uint)us[2] | ((uint)us[3] << 16);
    p.z = (uint)us[4] | ((uint)us[5] << 16);
    p.w = (uint)us[6] | ((uint)us[7] << 16);
    *(uint4*)&Bt[id * 8] = p;
  }
  __syncthreads();

  int wv = t >> 6, lane = t & 63;
  int r16 = lane & 15, kg = lane >> 4;
  int row0 = blockIdx.x * 128 + wv * 32;
  f32x4 acc[2][8] = {};

#pragma unroll
  for (int ks = 0; ks < 4; ++ks) {
    bf16x8 a0, a1;
    if (A_IS_F32) {
      const float* Af = (const float*)A;
      int r = min(row0 + r16, n - 1);
      const float* p = &Af[(size_t)r * 128 + ks * 32 + kg * 8];
      a0 = pack8(*(const float4*)p, *(const float4*)(p + 4));
      r = min(row0 + 16 + r16, n - 1);
      p = &Af[(size_t)r * 128 + ks * 32 + kg * 8];
      a1 = pack8(*(const float4*)p, *(const float4*)(p + 4));
    } else {
      const ushort* Ab = (const ushort*)A;
      int r = min(row0 + r16, n - 1);
      a0 = *(const bf16x8*)&Ab[(size_t)r * 128 + ks * 32 + kg * 8];
      r = min(row0 + 16 + r16, n - 1);
      a1 = *(const bf16x8*)&Ab[(size_t)r * 128 + ks * 32 + kg * 8];
    }
#pragma unroll
    for (int tc = 0; tc < 8; ++tc) {
      bf16x8 b = *(const bf16x8*)&Bt[(((ks * 4 + kg) * 128) + tc * 16 + r16) * 8];
      acc[0][tc] = __builtin_amdgcn_mfma_f32_16x16x32_bf16(a0, b, acc[0][tc], 0, 0, 0);
      acc[1][tc] = __builtin_amdgcn_mfma_f32_16x16x32_bf16(a1, b, acc[1][tc], 0, 0, 0);
    }
  }

#pragma unroll
  for (int rt = 0; rt < 2; ++rt)
#pragma unroll
    for (int tc = 0; tc < 8; ++tc)
#pragma unroll
      for (int rg = 0; rg < 4; ++rg) {
        int row = row0 + rt * 16 + kg * 4 + rg;
        if (row < n) H[(size_t)row * 128 + tc * 16 + r16] = f2bf(acc[rt][tc][rg]);
      }
}

// --------------------------- Aggregation -----------------------------------
// One wave per node; lane owns one packed bf16 pair (4B) -> 256B per row.
// MODE 0: out bf16 + relu (layer 1).  MODE 1: out fp32 (layer 2).

template <int MODE>
__global__ __launch_bounds__(256) void k_aggregate(
    const ushort* __restrict__ H, const int* __restrict__ csr_src,
    const int* __restrict__ row_ptr, const float* __restrict__ dinv,
    const float* __restrict__ bias, ushort* __restrict__ outb,
    float* __restrict__ outf, int n) {
  int node = (blockIdx.x * blockDim.x + threadIdx.x) >> 6;
  int lane = threadIdx.x & 63;
  if (node >= n) return;

  float di = dinv[node];
  int beg = row_ptr[node], end = row_ptr[node + 1];

  uint su = *(const uint*)&H[(size_t)node * 128 + lane * 2];
  float w0 = di * di;
  float ax = w0 * bf_lo(su), ay = w0 * bf_hi(su);

  int e = beg;
  for (; e + 1 < end; e += 2) {
    int s0 = csr_src[e], s1 = csr_src[e + 1];
    float q0 = di * dinv[s0], q1 = di * dinv[s1];
    uint u0 = *(const uint*)&H[(size_t)s0 * 128 + lane * 2];
    uint u1 = *(const uint*)&H[(size_t)s1 * 128 + lane * 2];
    ax = fmaf(q0, bf_lo(u0), ax); ay = fmaf(q0, bf_hi(u0), ay);
    ax = fmaf(q1, bf_lo(u1), ax); ay = fmaf(q1, bf_hi(u1), ay);
  }
  if (e < end) {
    int s0 = csr_src[e];
    float q0 = di * dinv[s0];
    uint u0 = *(const uint*)&H[(size_t)s0 * 128 + lane * 2];
    ax = fmaf(q0, bf_lo(u0), ax); ay = fmaf(q0, bf_hi(u0), ay);
  }

  float2 b = *(const float2*)&bias[lane * 2];
  ax += b.x; ay += b.y;
  if (MODE == 0) {
    ax = fmaxf(ax, 0.f); ay = fmaxf(ay, 0.f);
    uint o = (uint)f2bf(ax) | ((uint)f2bf(ay) << 16);
    *(uint*)&outb[(size_t)node * 128 + lane * 2] = o;
  } else {
    *(float2*)&outf[(size_t)node * 128 + lane * 2] = make_float2(ax, ay);
  }
}

// ---------------------------------------------------------------------------

extern "C" void kernel_launch(void* const* d_in, const int* in_sizes, int n_in,
                              void* d_out, int out_size, void* d_ws, size_t ws_size,
                              hipStream_t stream) {
  const float* x  = (const float*)d_in[0];
  const int* eidx = (const int*)d_in[1];
  const float* W1 = (const float*)d_in[2];
  const float* b1 = (const float*)d_in[3];
  const float* W2 = (const float*)d_in[4];
  const float* b2 = (const float*)d_in[5];
  float* out = (float*)d_out;

  const int N = in_sizes[0] / 128;
  const int E = in_sizes[1] / 2;
  const int* src = eidx;
  const int* dst = eidx + E;
  const int NBK = (N + BKT_NODES - 1) >> BKT_SHIFT;  // <= 1024 for N <= 512K

  auto align16 = [](size_t v) { return (v + 15) & ~(size_t)15; };
  char* w = (char*)d_ws;
  ushort* hb    = (ushort*)w; w += align16((size_t)N * 128 * 2);  // 25.6 MB
  ushort* h1b   = (ushort*)w; w += align16((size_t)N * 128 * 2);  // 25.6 MB
  int* csr_src  = (int*)w;    w += align16((size_t)E * 4);        // 6.4 MB
  int* row_ptr  = (int*)w;    w += align16((size_t)(N + 1) * 4);
  float* dinv   = (float*)w;  w += align16((size_t)N * 4);
  int* bcnt_g   = (int*)w;    w += align16((size_t)(NBK + 1) * 4);
  int* bbase    = (int*)w;    w += align16((size_t)(NBK + 1) * 4);
  int* bcur     = (int*)w;    w += align16((size_t)(NBK + 1) * 4);
  // ebuf (E*4 bytes) aliases h1b: consumed by k_bktcsr before aggregate-1
  // writes h1b (stream-ordered).
  uint* ebuf = (uint*)h1b;

  hipMemsetAsync(bcnt_g, 0, (size_t)NBK * 4, stream);
  k_bktcnt<<<256, 256, 0, stream>>>(dst, bcnt_g, E, NBK);
  k_bktscan<<<1, 1024, 0, stream>>>(bcnt_g, bbase, bcur, NBK, E, row_ptr, N);
  k_bktscatter<<<256, 256, 0, stream>>>(src, dst, bcur, ebuf, E, NBK);
  k_bktcsr<<<NBK, 256, 0, stream>>>(ebuf, bbase, row_ptr, dinv, csr_src, N);

  const int GB = (N + 127) / 128;
  // layer 1: hb = bf16(X @ W1); h1b = bf16(relu(Ahat hb + b1))
  k_gemm_mfma<true><<<GB, 256, 0, stream>>>(x, W1, hb, N);
  k_aggregate<0><<<(N * 64 + 255) / 256, 256, 0, stream>>>(
      hb, csr_src, row_ptr, dinv, b1, h1b, nullptr, N);
  // layer 2: hb = bf16(h1b @ W2); out = Ahat hb + b2 (fp32)
  k_gemm_mfma<false><<<GB, 256, 0, stream>>>(h1b, W2, hb, N);
  k_aggregate<1><<<(N * 64 + 255) / 256, 256, 0, stream>>>(
      hb, csr_src, row_ptr, dinv, b2, nullptr, out, N);
}

// Round 5
// 249.922 us; speedup vs baseline: 3.5983x; 1.2518x over previous
//
#include <hip/hip_runtime.h>

// ---------------------------------------------------------------------------
// 2-layer GCN:  out = Ahat * (relu(Ahat * X * W1 + b1)) * W2 + b2
// Ahat = D^-1/2 (A + I) D^-1/2, deg computed with self-loops.
//
// Round-5: aggregate restructured to 4 nodes/wave (16 lanes x uint4 per row)
// -> 4x gather bytes per instruction, ~2.8x fewer wave-iterations, 4x MLP.
// (Round-4 profile: k_aggregate 104us each, VALUBusy 33%, fill BW 1.9 TB/s
// -> latency-bound, not path-saturated.)
// ---------------------------------------------------------------------------

typedef __attribute__((ext_vector_type(8))) short bf16x8;
typedef __attribute__((ext_vector_type(4))) float f32x4;
typedef unsigned int uint;
typedef unsigned short ushort;

#define BKT_SHIFT 9
#define BKT_NODES 512   // nodes per bucket; NBK = ceil(N/512) <= 1024

__device__ __forceinline__ ushort f2bf(float f) {  // RNE f32 -> bf16
  union { float f; uint u; } c; c.f = f;
  uint u = c.u;
  uint r = u + 0x7fffu + ((u >> 16) & 1u);
  return (ushort)(r >> 16);
}
__device__ __forceinline__ float bf_lo(uint u) {
  union { uint i; float f; } c; c.i = u << 16; return c.f;
}
__device__ __forceinline__ float bf_hi(uint u) {
  union { uint i; float f; } c; c.i = u & 0xffff0000u; return c.f;
}

// --------------------------- CSR build (bucketed) --------------------------

__global__ __launch_bounds__(256) void k_bktcnt(const int* __restrict__ dst,
                                                int* __restrict__ bcnt_g,
                                                int E, int nbk) {
  __shared__ int h[1024];
  int t = threadIdx.x;
  for (int i = t; i < nbk; i += 256) h[i] = 0;
  __syncthreads();
  int chunk = (E + gridDim.x - 1) / gridDim.x;
  int beg = blockIdx.x * chunk, end = min(E, beg + chunk);
  for (int e = beg + t; e < end; e += 256)
    atomicAdd(&h[dst[e] >> BKT_SHIFT], 1);
  __syncthreads();
  for (int i = t; i < nbk; i += 256)
    if (h[i]) atomicAdd(&bcnt_g[i], h[i]);
}

__global__ __launch_bounds__(1024) void k_bktscan(const int* __restrict__ bcnt_g,
                                                  int* __restrict__ bbase,
                                                  int* __restrict__ bcur,
                                                  int nbk, int E,
                                                  int* __restrict__ row_ptr, int N) {
  __shared__ int s[1024];
  int t = threadIdx.x;
  s[t] = (t < nbk) ? bcnt_g[t] : 0;
  __syncthreads();
  for (int off = 1; off < 1024; off <<= 1) {
    int u = 0;
    if (t >= off) u = s[t - off];
    __syncthreads();
    if (t >= off) s[t] += u;
    __syncthreads();
  }
  if (t < nbk) {
    int ex = (t == 0) ? 0 : s[t - 1];
    bbase[t] = ex;
    bcur[t] = ex;
  }
  if (t == 0) { bbase[nbk] = E; row_ptr[N] = E; }
}

__global__ __launch_bounds__(256) void k_bktscatter(const int* __restrict__ src,
                                                    const int* __restrict__ dst,
                                                    int* __restrict__ bcur,
                                                    uint* __restrict__ ebuf,
                                                    int E, int nbk) {
  __shared__ int h[1024];
  __shared__ int rbase[1024];
  int t = threadIdx.x;
  for (int i = t; i < nbk; i += 256) h[i] = 0;
  __syncthreads();
  int chunk = (E + gridDim.x - 1) / gridDim.x;
  int beg = blockIdx.x * chunk, end = min(E, beg + chunk);
  for (int e = beg + t; e < end; e += 256)
    atomicAdd(&h[dst[e] >> BKT_SHIFT], 1);
  __syncthreads();
  for (int i = t; i < nbk; i += 256) {
    int c = h[i];
    rbase[i] = c ? atomicAdd(&bcur[i], c) : 0;
    h[i] = 0;  // reuse as per-block cursor
  }
  __syncthreads();
  for (int e = beg + t; e < end; e += 256) {
    int d = dst[e];
    int b = d >> BKT_SHIFT;
    int pos = rbase[b] + atomicAdd(&h[b], 1);
    ebuf[pos] = ((uint)src[e] << BKT_SHIFT) | (uint)(d & (BKT_NODES - 1));
  }
}

__global__ __launch_bounds__(256) void k_bktcsr(const uint* __restrict__ ebuf,
                                                const int* __restrict__ bbase,
                                                int* __restrict__ row_ptr,
                                                float* __restrict__ dinv,
                                                int* __restrict__ csr_src, int N) {
  __shared__ int ncnt[BKT_NODES];
  __shared__ int nscan[BKT_NODES];
  __shared__ int ncur[BKT_NODES];
  __shared__ int wtot[4];
  int t = threadIdx.x;
  int b = blockIdx.x;
  int node0 = b << BKT_SHIFT;
  int ebase = bbase[b];
  int eend = bbase[b + 1];
  ncnt[t] = 0; ncnt[t + 256] = 0;
  ncur[t] = 0; ncur[t + 256] = 0;
  __syncthreads();
  for (int e = ebase + t; e < eend; e += 256)
    atomicAdd(&ncnt[ebuf[e] & (BKT_NODES - 1)], 1);
  __syncthreads();
  int v0 = ncnt[2 * t], v1 = ncnt[2 * t + 1];
  int s = v0 + v1;
  int lane = t & 63, wv = t >> 6;
  int inc = s;
#pragma unroll
  for (int off = 1; off < 64; off <<= 1) {
    int u = __shfl_up(inc, off);
    if (lane >= off) inc += u;
  }
  if (lane == 63) wtot[wv] = inc;
  __syncthreads();
  int woff = 0;
  for (int i = 0; i < wv; ++i) woff += wtot[i];
  int ex = woff + inc - s;
  nscan[2 * t] = ex;
  nscan[2 * t + 1] = ex + v0;
  int n0 = node0 + 2 * t;
  if (n0 < N) {
    row_ptr[n0] = ebase + ex;
    dinv[n0] = rsqrtf((float)v0 + 1.0f);
  }
  if (n0 + 1 < N) {
    row_ptr[n0 + 1] = ebase + ex + v0;
    dinv[n0 + 1] = rsqrtf((float)v1 + 1.0f);
  }
  __syncthreads();
  for (int e = ebase + t; e < eend; e += 256) {
    uint u = ebuf[e];
    int l = u & (BKT_NODES - 1);
    int pos = ebase + nscan[l] + atomicAdd(&ncur[l], 1);
    csr_src[pos] = (int)(u >> BKT_SHIFT);
  }
}

// --------------------------- MFMA GEMM -------------------------------------

__device__ __forceinline__ bf16x8 pack8(float4 u, float4 v) {
  bf16x8 r;
  r[0] = (short)f2bf(u.x); r[1] = (short)f2bf(u.y);
  r[2] = (short)f2bf(u.z); r[3] = (short)f2bf(u.w);
  r[4] = (short)f2bf(v.x); r[5] = (short)f2bf(v.y);
  r[6] = (short)f2bf(v.z); r[7] = (short)f2bf(v.w);
  return r;
}

template <bool A_IS_F32>
__global__ __launch_bounds__(256) void k_gemm_mfma(const void* __restrict__ A,
                                                   const float* __restrict__ Wf,
                                                   ushort* __restrict__ H, int n) {
  __shared__ __align__(16) ushort Bt[16 * 128 * 8];  // [chunk][col][8]
  int t = threadIdx.x;
  for (int id = t; id < 16 * 128; id += 256) {
    int col = id & 127, ch = id >> 7;
    ushort us[8];
#pragma unroll
    for (int j = 0; j < 8; ++j) us[j] = f2bf(Wf[(ch * 8 + j) * 128 + col]);
    uint4 p;
    p.x = (uint)us[0] | ((uint)us[1] << 16);
    p.y = (uint)us[2] | ((uint)us[3] << 16);
    p.z = (uint)us[4] | ((uint)us[5] << 16);
    p.w = (uint)us[6] | ((uint)us[7] << 16);
    *(uint4*)&Bt[id * 8] = p;
  }
  __syncthreads();

  int wv = t >> 6, lane = t & 63;
  int r16 = lane & 15, kg = lane >> 4;
  int row0 = blockIdx.x * 128 + wv * 32;
  f32x4 acc[2][8] = {};

#pragma unroll
  for (int ks = 0; ks < 4; ++ks) {
    bf16x8 a0, a1;
    if (A_IS_F32) {
      const float* Af = (const float*)A;
      int r = min(row0 + r16, n - 1);
      const float* p = &Af[(size_t)r * 128 + ks * 32 + kg * 8];
      a0 = pack8(*(const float4*)p, *(const float4*)(p + 4));
      r = min(row0 + 16 + r16, n - 1);
      p = &Af[(size_t)r * 128 + ks * 32 + kg * 8];
      a1 = pack8(*(const float4*)p, *(const float4*)(p + 4));
    } else {
      const ushort* Ab = (const ushort*)A;
      int r = min(row0 + r16, n - 1);
      a0 = *(const bf16x8*)&Ab[(size_t)r * 128 + ks * 32 + kg * 8];
      r = min(row0 + 16 + r16, n - 1);
      a1 = *(const bf16x8*)&Ab[(size_t)r * 128 + ks * 32 + kg * 8];
    }
#pragma unroll
    for (int tc = 0; tc < 8; ++tc) {
      bf16x8 b = *(const bf16x8*)&Bt[(((ks * 4 + kg) * 128) + tc * 16 + r16) * 8];
      acc[0][tc] = __builtin_amdgcn_mfma_f32_16x16x32_bf16(a0, b, acc[0][tc], 0, 0, 0);
      acc[1][tc] = __builtin_amdgcn_mfma_f32_16x16x32_bf16(a1, b, acc[1][tc], 0, 0, 0);
    }
  }

#pragma unroll
  for (int rt = 0; rt < 2; ++rt)
#pragma unroll
    for (int tc = 0; tc < 8; ++tc)
#pragma unroll
      for (int rg = 0; rg < 4; ++rg) {
        int row = row0 + rt * 16 + kg * 4 + rg;
        if (row < n) H[(size_t)row * 128 + tc * 16 + r16] = f2bf(acc[rt][tc][rg]);
      }
}

// --------------------------- Aggregation -----------------------------------
// 4 nodes per wave: sub = lane>>4 owns node base+sub; lane&15 covers 16B
// (8 bf16 cols) of the 256B row -> one dwordx4 gathers 4 rows (1KB/instr).
// MODE 0: out bf16 + relu (layer 1).  MODE 1: out fp32 (layer 2).

__device__ __forceinline__ void fma8(float q, uint4 u, float* a) {
  a[0] = fmaf(q, bf_lo(u.x), a[0]);
  a[1] = fmaf(q, bf_hi(u.x), a[1]);
  a[2] = fmaf(q, bf_lo(u.y), a[2]);
  a[3] = fmaf(q, bf_hi(u.y), a[3]);
  a[4] = fmaf(q, bf_lo(u.z), a[4]);
  a[5] = fmaf(q, bf_hi(u.z), a[5]);
  a[6] = fmaf(q, bf_lo(u.w), a[6]);
  a[7] = fmaf(q, bf_hi(u.w), a[7]);
}

template <int MODE>
__global__ __launch_bounds__(256) void k_aggregate(
    const ushort* __restrict__ H, const int* __restrict__ csr_src,
    const int* __restrict__ row_ptr, const float* __restrict__ dinv,
    const float* __restrict__ bias, ushort* __restrict__ outb,
    float* __restrict__ outf, int n) {
  int wave = (blockIdx.x * blockDim.x + threadIdx.x) >> 6;
  int lane = threadIdx.x & 63;
  int sub = lane >> 4, c16 = lane & 15;
  int node = wave * 4 + sub;
  bool valid = node < n;
  int nd = valid ? node : (n - 1);

  float di = dinv[nd];
  int beg = row_ptr[nd];
  int end = valid ? row_ptr[nd + 1] : beg;

  // self loop
  uint4 sv = *(const uint4*)&H[(size_t)nd * 128 + c16 * 8];
  float acc[8] = {};
  fma8(di * di, sv, acc);

  int e = beg;
  for (; e + 1 < end; e += 2) {
    int s0 = csr_src[e], s1 = csr_src[e + 1];
    float q0 = di * dinv[s0], q1 = di * dinv[s1];
    uint4 u0 = *(const uint4*)&H[(size_t)s0 * 128 + c16 * 8];
    uint4 u1 = *(const uint4*)&H[(size_t)s1 * 128 + c16 * 8];
    fma8(q0, u0, acc);
    fma8(q1, u1, acc);
  }
  if (e < end) {
    int s0 = csr_src[e];
    float q0 = di * dinv[s0];
    uint4 u0 = *(const uint4*)&H[(size_t)s0 * 128 + c16 * 8];
    fma8(q0, u0, acc);
  }

  float4 bA = *(const float4*)&bias[c16 * 8];
  float4 bB = *(const float4*)&bias[c16 * 8 + 4];
  acc[0] += bA.x; acc[1] += bA.y; acc[2] += bA.z; acc[3] += bA.w;
  acc[4] += bB.x; acc[5] += bB.y; acc[6] += bB.z; acc[7] += bB.w;

  if (!valid) return;
  if (MODE == 0) {
#pragma unroll
    for (int i = 0; i < 8; ++i) acc[i] = fmaxf(acc[i], 0.f);
    uint4 o;
    o.x = (uint)f2bf(acc[0]) | ((uint)f2bf(acc[1]) << 16);
    o.y = (uint)f2bf(acc[2]) | ((uint)f2bf(acc[3]) << 16);
    o.z = (uint)f2bf(acc[4]) | ((uint)f2bf(acc[5]) << 16);
    o.w = (uint)f2bf(acc[6]) | ((uint)f2bf(acc[7]) << 16);
    *(uint4*)&outb[(size_t)node * 128 + c16 * 8] = o;
  } else {
    *(float4*)&outf[(size_t)node * 128 + c16 * 8] =
        make_float4(acc[0], acc[1], acc[2], acc[3]);
    *(float4*)&outf[(size_t)node * 128 + c16 * 8 + 4] =
        make_float4(acc[4], acc[5], acc[6], acc[7]);
  }
}

// ---------------------------------------------------------------------------

extern "C" void kernel_launch(void* const* d_in, const int* in_sizes, int n_in,
                              void* d_out, int out_size, void* d_ws, size_t ws_size,
                              hipStream_t stream) {
  const float* x  = (const float*)d_in[0];
  const int* eidx = (const int*)d_in[1];
  const float* W1 = (const float*)d_in[2];
  const float* b1 = (const float*)d_in[3];
  const float* W2 = (const float*)d_in[4];
  const float* b2 = (const float*)d_in[5];
  float* out = (float*)d_out;

  const int N = in_sizes[0] / 128;
  const int E = in_sizes[1] / 2;
  const int* src = eidx;
  const int* dst = eidx + E;
  const int NBK = (N + BKT_NODES - 1) >> BKT_SHIFT;

  auto align16 = [](size_t v) { return (v + 15) & ~(size_t)15; };
  char* w = (char*)d_ws;
  ushort* hb    = (ushort*)w; w += align16((size_t)N * 128 * 2);  // 25.6 MB
  ushort* h1b   = (ushort*)w; w += align16((size_t)N * 128 * 2);  // 25.6 MB
  int* csr_src  = (int*)w;    w += align16((size_t)E * 4);        // 6.4 MB
  int* row_ptr  = (int*)w;    w += align16((size_t)(N + 1) * 4);
  float* dinv   = (float*)w;  w += align16((size_t)N * 4);
  int* bcnt_g   = (int*)w;    w += align16((size_t)(NBK + 1) * 4);
  int* bbase    = (int*)w;    w += align16((size_t)(NBK + 1) * 4);
  int* bcur     = (int*)w;    w += align16((size_t)(NBK + 1) * 4);
  uint* ebuf = (uint*)h1b;  // consumed by k_bktcsr before aggregate-1 writes h1b

  hipMemsetAsync(bcnt_g, 0, (size_t)NBK * 4, stream);
  k_bktcnt<<<256, 256, 0, stream>>>(dst, bcnt_g, E, NBK);
  k_bktscan<<<1, 1024, 0, stream>>>(bcnt_g, bbase, bcur, NBK, E, row_ptr, N);
  k_bktscatter<<<256, 256, 0, stream>>>(src, dst, bcur, ebuf, E, NBK);
  k_bktcsr<<<NBK, 256, 0, stream>>>(ebuf, bbase, row_ptr, dinv, csr_src, N);

  const int GB = (N + 127) / 128;
  const int AGG_WAVES = (N + 3) / 4;
  const int AGG_BLOCKS = (AGG_WAVES + 3) / 4;  // 4 waves (256 thr) per block
  // layer 1: hb = bf16(X @ W1); h1b = bf16(relu(Ahat hb + b1))
  k_gemm_mfma<true><<<GB, 256, 0, stream>>>(x, W1, hb, N);
  k_aggregate<0><<<AGG_BLOCKS, 256, 0, stream>>>(
      hb, csr_src, row_ptr, dinv, b1, h1b, nullptr, N);
  // layer 2: hb = bf16(h1b @ W2); out = Ahat hb + b2 (fp32)
  k_gemm_mfma<false><<<GB, 256, 0, stream>>>(h1b, W2, hb, N);
  k_aggregate<1><<<AGG_BLOCKS, 256, 0, stream>>>(
      hb, csr_src, row_ptr, dinv, b2, nullptr, out, N);
}

// Round 6
// 224.222 us; speedup vs baseline: 4.0108x; 1.1146x over previous
//
#include <hip/hip_runtime.h>

// ---------------------------------------------------------------------------
// 2-layer GCN:  out = Ahat * (relu(Ahat * X * W1 + b1)) * W2 + b2
// Ahat = D^-1/2 (A + I) D^-1/2, deg computed with self-loops.
//
// Round-6:
//  * h stored PRE-SCALED: h' = dinv[row] * (A@W) in bf16 (GEMM epilogue).
//    Aggregate inner loop is then: gather h'[src], accumulate, final *dinv[i]
//    -> removes the dependent per-edge dinv[src] random load entirely.
//  * gather loop unrolled 4 edges (16 outstanding dwordx4 per wave).
//  * single-pass CSR: padded-bucket scatter with per-block reservations
//    (no pre-count kernel), scan over final cursors, bucket-local CSR.
// ---------------------------------------------------------------------------

typedef __attribute__((ext_vector_type(8))) short bf16x8;
typedef __attribute__((ext_vector_type(4))) float f32x4;
typedef unsigned int uint;
typedef unsigned short ushort;

#define BKT_SHIFT 9
#define BKT_NODES 512   // nodes per bucket; NBK = ceil(N/512) <= 1024

__device__ __forceinline__ ushort f2bf(float f) {  // RNE f32 -> bf16
  union { float f; uint u; } c; c.f = f;
  uint u = c.u;
  uint r = u + 0x7fffu + ((u >> 16) & 1u);
  return (ushort)(r >> 16);
}
__device__ __forceinline__ float bf_lo(uint u) {
  union { uint i; float f; } c; c.i = u << 16; return c.f;
}
__device__ __forceinline__ float bf_hi(uint u) {
  union { uint i; float f; } c; c.i = u & 0xffff0000u; return c.f;
}

// --------------------------- CSR build (single-pass, padded buckets) -------

__global__ __launch_bounds__(256) void k_initbcur(int* __restrict__ bcur,
                                                  int nbk, int cap) {
  int i = blockIdx.x * 256 + threadIdx.x;
  if (i < nbk) bcur[i] = i * cap;
}

// Scatter edges into padded bucket regions. Per-block LDS histogram ->
// one global reservation atomic per (block,bucket) -> packed writes.
__global__ __launch_bounds__(256) void k_bktscatter(const int* __restrict__ src,
                                                    const int* __restrict__ dst,
                                                    int* __restrict__ bcur,
                                                    uint* __restrict__ ebuf,
                                                    int E, int nbk, int cap) {
  __shared__ int h[1024];
  __shared__ int rbase[1024];
  int t = threadIdx.x;
  for (int i = t; i < nbk; i += 256) h[i] = 0;
  __syncthreads();
  int chunk = (E + gridDim.x - 1) / gridDim.x;
  int beg = blockIdx.x * chunk, end = min(E, beg + chunk);
  for (int e = beg + t; e < end; e += 256)
    atomicAdd(&h[dst[e] >> BKT_SHIFT], 1);
  __syncthreads();
  for (int i = t; i < nbk; i += 256) {
    int c = h[i];
    rbase[i] = c ? atomicAdd(&bcur[i], c) : 0;  // absolute padded position
    h[i] = 0;  // reuse as per-block cursor
  }
  __syncthreads();
  for (int e = beg + t; e < end; e += 256) {
    int d = dst[e];
    int b = d >> BKT_SHIFT;
    int pos = rbase[b] + atomicAdd(&h[b], 1);
    if (pos < (b + 1) * cap)  // overflow guard (CAP = 1.5x mean, ~+45 sigma)
      ebuf[pos] = ((uint)src[e] << BKT_SHIFT) | (uint)(d & (BKT_NODES - 1));
  }
}

// Exclusive scan of bucket counts (derived from final cursors) -> bbase.
__global__ __launch_bounds__(1024) void k_bktscan(const int* __restrict__ bcur,
                                                  int* __restrict__ bbase,
                                                  int nbk, int cap,
                                                  int* __restrict__ row_ptr, int N) {
  __shared__ int s[1024];
  int t = threadIdx.x;
  int c = 0;
  if (t < nbk) c = min(bcur[t] - t * cap, cap);
  s[t] = c;
  __syncthreads();
  for (int off = 1; off < 1024; off <<= 1) {
    int u = 0;
    if (t >= off) u = s[t - off];
    __syncthreads();
    if (t >= off) s[t] += u;
    __syncthreads();
  }
  if (t < nbk) bbase[t] = s[t] - c;            // exclusive
  if (t == nbk - 1) { bbase[nbk] = s[t]; row_ptr[N] = s[t]; }
}

// One block per bucket: LDS node-histogram -> scan -> row_ptr/dinv -> compact
// csr_src scatter confined to the bucket's contiguous output region.
__global__ __launch_bounds__(256) void k_bktcsr(const uint* __restrict__ ebuf,
                                                const int* __restrict__ bbase,
                                                int cap,
                                                int* __restrict__ row_ptr,
                                                float* __restrict__ dinv,
                                                int* __restrict__ csr_src, int N) {
  __shared__ int ncnt[BKT_NODES];
  __shared__ int nscan[BKT_NODES];
  __shared__ int ncur[BKT_NODES];
  __shared__ int wtot[4];
  int t = threadIdx.x;
  int b = blockIdx.x;
  int node0 = b << BKT_SHIFT;
  int ebase = bbase[b];
  int cnt = bbase[b + 1] - ebase;
  const uint* ein = ebuf + (size_t)b * cap;
  ncnt[t] = 0; ncnt[t + 256] = 0;
  ncur[t] = 0; ncur[t + 256] = 0;
  __syncthreads();
  for (int e = t; e < cnt; e += 256)
    atomicAdd(&ncnt[ein[e] & (BKT_NODES - 1)], 1);
  __syncthreads();
  int v0 = ncnt[2 * t], v1 = ncnt[2 * t + 1];
  int s = v0 + v1;
  int lane = t & 63, wv = t >> 6;
  int inc = s;
#pragma unroll
  for (int off = 1; off < 64; off <<= 1) {
    int u = __shfl_up(inc, off);
    if (lane >= off) inc += u;
  }
  if (lane == 63) wtot[wv] = inc;
  __syncthreads();
  int woff = 0;
  for (int i = 0; i < wv; ++i) woff += wtot[i];
  int ex = woff + inc - s;
  nscan[2 * t] = ex;
  nscan[2 * t + 1] = ex + v0;
  int n0 = node0 + 2 * t;
  if (n0 < N) {
    row_ptr[n0] = ebase + ex;
    dinv[n0] = rsqrtf((float)v0 + 1.0f);
  }
  if (n0 + 1 < N) {
    row_ptr[n0 + 1] = ebase + ex + v0;
    dinv[n0 + 1] = rsqrtf((float)v1 + 1.0f);
  }
  __syncthreads();
  for (int e = t; e < cnt; e += 256) {
    uint u = ein[e];
    int l = u & (BKT_NODES - 1);
    int pos = ebase + nscan[l] + atomicAdd(&ncur[l], 1);
    csr_src[pos] = (int)(u >> BKT_SHIFT);
  }
}

// --------------------------- MFMA GEMM (dinv-scaled epilogue) --------------
// H'[n,128](bf16) = dinv[row] * (A[n,128] @ W[128,128]).
// A fp32 (layer1: X) or bf16 (layer2: h1). W staged in LDS chunk-major
// Bt[k/8][col][8]; frag layouts per m89 (A row=lane&15 k=(lane>>4)*8+j;
// B col=lane&15; D col=lane&15, row=(lane>>4)*4+reg).

__device__ __forceinline__ bf16x8 pack8(float4 u, float4 v) {
  bf16x8 r;
  r[0] = (short)f2bf(u.x); r[1] = (short)f2bf(u.y);
  r[2] = (short)f2bf(u.z); r[3] = (short)f2bf(u.w);
  r[4] = (short)f2bf(v.x); r[5] = (short)f2bf(v.y);
  r[6] = (short)f2bf(v.z); r[7] = (short)f2bf(v.w);
  return r;
}

template <bool A_IS_F32>
__global__ __launch_bounds__(256) void k_gemm_mfma(const void* __restrict__ A,
                                                   const float* __restrict__ Wf,
                                                   const float* __restrict__ dinv,
                                                   ushort* __restrict__ H, int n) {
  __shared__ __align__(16) ushort Bt[16 * 128 * 8];  // [chunk][col][8]
  int t = threadIdx.x;
  for (int id = t; id < 16 * 128; id += 256) {
    int col = id & 127, ch = id >> 7;
    ushort us[8];
#pragma unroll
    for (int j = 0; j < 8; ++j) us[j] = f2bf(Wf[(ch * 8 + j) * 128 + col]);
    uint4 p;
    p.x = (uint)us[0] | ((uint)us[1] << 16);
    p.y = (uint)us[2] | ((uint)us[3] << 16);
    p.z = (uint)us[4] | ((uint)us[5] << 16);
    p.w = (uint)us[6] | ((uint)us[7] << 16);
    *(uint4*)&Bt[id * 8] = p;
  }
  __syncthreads();

  int wv = t >> 6, lane = t & 63;
  int r16 = lane & 15, kg = lane >> 4;
  int row0 = blockIdx.x * 128 + wv * 32;
  f32x4 acc[2][8] = {};

#pragma unroll
  for (int ks = 0; ks < 4; ++ks) {
    bf16x8 a0, a1;
    if (A_IS_F32) {
      const float* Af = (const float*)A;
      int r = min(row0 + r16, n - 1);
      const float* p = &Af[(size_t)r * 128 + ks * 32 + kg * 8];
      a0 = pack8(*(const float4*)p, *(const float4*)(p + 4));
      r = min(row0 + 16 + r16, n - 1);
      p = &Af[(size_t)r * 128 + ks * 32 + kg * 8];
      a1 = pack8(*(const float4*)p, *(const float4*)(p + 4));
    } else {
      const ushort* Ab = (const ushort*)A;
      int r = min(row0 + r16, n - 1);
      a0 = *(const bf16x8*)&Ab[(size_t)r * 128 + ks * 32 + kg * 8];
      r = min(row0 + 16 + r16, n - 1);
      a1 = *(const bf16x8*)&Ab[(size_t)r * 128 + ks * 32 + kg * 8];
    }
#pragma unroll
    for (int tc = 0; tc < 8; ++tc) {
      bf16x8 b = *(const bf16x8*)&Bt[(((ks * 4 + kg) * 128) + tc * 16 + r16) * 8];
      acc[0][tc] = __builtin_amdgcn_mfma_f32_16x16x32_bf16(a0, b, acc[0][tc], 0, 0, 0);
      acc[1][tc] = __builtin_amdgcn_mfma_f32_16x16x32_bf16(a1, b, acc[1][tc], 0, 0, 0);
    }
  }

#pragma unroll
  for (int rt = 0; rt < 2; ++rt)
#pragma unroll
    for (int rg = 0; rg < 4; ++rg) {
      int row = row0 + rt * 16 + kg * 4 + rg;
      if (row < n) {
        float dv = dinv[row];
#pragma unroll
        for (int tc = 0; tc < 8; ++tc)
          H[(size_t)row * 128 + tc * 16 + r16] = f2bf(dv * acc[rt][tc][rg]);
      }
    }
}

// --------------------------- Aggregation -----------------------------------
// 4 nodes/wave: sub=lane>>4 owns node, lane&15 covers 16B (8 bf16 cols).
// H is pre-scaled by dinv[src], so inner loop = gather + 8 adds per edge.
// out_i = dinv_i * (h'_i + sum h'_src) + bias.
// MODE 0: out bf16 + relu (layer 1, unscaled).  MODE 1: out fp32 (layer 2).

__device__ __forceinline__ void add8(uint4 u, float* a) {
  a[0] += bf_lo(u.x); a[1] += bf_hi(u.x);
  a[2] += bf_lo(u.y); a[3] += bf_hi(u.y);
  a[4] += bf_lo(u.z); a[5] += bf_hi(u.z);
  a[6] += bf_lo(u.w); a[7] += bf_hi(u.w);
}

template <int MODE>
__global__ __launch_bounds__(256) void k_aggregate(
    const ushort* __restrict__ H, const int* __restrict__ csr_src,
    const int* __restrict__ row_ptr, const float* __restrict__ dinv,
    const float* __restrict__ bias, ushort* __restrict__ outb,
    float* __restrict__ outf, int n) {
  int wave = (blockIdx.x * blockDim.x + threadIdx.x) >> 6;
  int lane = threadIdx.x & 63;
  int sub = lane >> 4, c16 = lane & 15;
  int node = wave * 4 + sub;
  bool valid = node < n;
  int nd = valid ? node : (n - 1);

  float di = dinv[nd];
  int beg = row_ptr[nd];
  int end = valid ? row_ptr[nd + 1] : beg;

  float acc[8] = {};
  uint4 sv = *(const uint4*)&H[(size_t)nd * 128 + c16 * 8];  // self (pre-scaled)
  add8(sv, acc);

  int e = beg;
  for (; e + 3 < end; e += 4) {
    int s0 = csr_src[e], s1 = csr_src[e + 1];
    int s2 = csr_src[e + 2], s3 = csr_src[e + 3];
    uint4 u0 = *(const uint4*)&H[(size_t)s0 * 128 + c16 * 8];
    uint4 u1 = *(const uint4*)&H[(size_t)s1 * 128 + c16 * 8];
    uint4 u2 = *(const uint4*)&H[(size_t)s2 * 128 + c16 * 8];
    uint4 u3 = *(const uint4*)&H[(size_t)s3 * 128 + c16 * 8];
    add8(u0, acc); add8(u1, acc); add8(u2, acc); add8(u3, acc);
  }
  for (; e < end; ++e) {
    int s0 = csr_src[e];
    uint4 u0 = *(const uint4*)&H[(size_t)s0 * 128 + c16 * 8];
    add8(u0, acc);
  }

  float4 bA = *(const float4*)&bias[c16 * 8];
  float4 bB = *(const float4*)&bias[c16 * 8 + 4];
  float o[8];
  o[0] = fmaf(di, acc[0], bA.x); o[1] = fmaf(di, acc[1], bA.y);
  o[2] = fmaf(di, acc[2], bA.z); o[3] = fmaf(di, acc[3], bA.w);
  o[4] = fmaf(di, acc[4], bB.x); o[5] = fmaf(di, acc[5], bB.y);
  o[6] = fmaf(di, acc[6], bB.z); o[7] = fmaf(di, acc[7], bB.w);

  if (!valid) return;
  if (MODE == 0) {
#pragma unroll
    for (int i = 0; i < 8; ++i) o[i] = fmaxf(o[i], 0.f);
    uint4 w;
    w.x = (uint)f2bf(o[0]) | ((uint)f2bf(o[1]) << 16);
    w.y = (uint)f2bf(o[2]) | ((uint)f2bf(o[3]) << 16);
    w.z = (uint)f2bf(o[4]) | ((uint)f2bf(o[5]) << 16);
    w.w = (uint)f2bf(o[6]) | ((uint)f2bf(o[7]) << 16);
    *(uint4*)&outb[(size_t)node * 128 + c16 * 8] = w;
  } else {
    *(float4*)&outf[(size_t)node * 128 + c16 * 8] =
        make_float4(o[0], o[1], o[2], o[3]);
    *(float4*)&outf[(size_t)node * 128 + c16 * 8 + 4] =
        make_float4(o[4], o[5], o[6], o[7]);
  }
}

// ---------------------------------------------------------------------------

extern "C" void kernel_launch(void* const* d_in, const int* in_sizes, int n_in,
                              void* d_out, int out_size, void* d_ws, size_t ws_size,
                              hipStream_t stream) {
  const float* x  = (const float*)d_in[0];
  const int* eidx = (const int*)d_in[1];
  const float* W1 = (const float*)d_in[2];
  const float* b1 = (const float*)d_in[3];
  const float* W2 = (const float*)d_in[4];
  const float* b2 = (const float*)d_in[5];
  float* out = (float*)d_out;

  const int N = in_sizes[0] / 128;
  const int E = in_sizes[1] / 2;
  const int* src = eidx;
  const int* dst = eidx + E;
  const int NBK = (N + BKT_NODES - 1) >> BKT_SHIFT;
  const int CAP = (((E / NBK) * 3 / 2) + 255) & ~255;  // padded bucket capacity

  auto align16 = [](size_t v) { return (v + 15) & ~(size_t)15; };
  char* w = (char*)d_ws;
  ushort* hb    = (ushort*)w; w += align16((size_t)N * 128 * 2);  // 25.6 MB
  ushort* h1b   = (ushort*)w; w += align16((size_t)N * 128 * 2);  // 25.6 MB
  int* csr_src  = (int*)w;    w += align16((size_t)E * 4);        // 6.4 MB
  int* row_ptr  = (int*)w;    w += align16((size_t)(N + 1) * 4);
  float* dinv   = (float*)w;  w += align16((size_t)N * 4);
  int* bbase    = (int*)w;    w += align16((size_t)(NBK + 1) * 4);
  int* bcur     = (int*)w;    w += align16((size_t)(NBK + 1) * 4);
  // padded edge buffer aliases h1b (NBK*CAP*4 ~ 9.6 MB < 25.6 MB); consumed
  // by k_bktcsr before aggregate-1 writes h1b (stream-ordered).
  uint* ebuf = (uint*)h1b;

  k_initbcur<<<(NBK + 255) / 256, 256, 0, stream>>>(bcur, NBK, CAP);
  k_bktscatter<<<256, 256, 0, stream>>>(src, dst, bcur, ebuf, E, NBK, CAP);
  k_bktscan<<<1, 1024, 0, stream>>>(bcur, bbase, NBK, CAP, row_ptr, N);
  k_bktcsr<<<NBK, 256, 0, stream>>>(ebuf, bbase, CAP, row_ptr, dinv, csr_src, N);

  const int GB = (N + 127) / 128;
  const int AGG_BLOCKS = ((N + 3) / 4 + 3) / 4;  // 4 nodes/wave, 4 waves/block
  // layer 1: hb = bf16(dinv * (X @ W1)); h1b = bf16(relu(dinv*sum + b1))
  k_gemm_mfma<true><<<GB, 256, 0, stream>>>(x, W1, dinv, hb, N);
  k_aggregate<0><<<AGG_BLOCKS, 256, 0, stream>>>(
      hb, csr_src, row_ptr, dinv, b1, h1b, nullptr, N);
  // layer 2: hb = bf16(dinv * (h1b @ W2)); out = dinv*sum + b2 (fp32)
  k_gemm_mfma<false><<<GB, 256, 0, stream>>>(h1b, W2, dinv, hb, N);
  k_aggregate<1><<<AGG_BLOCKS, 256, 0, stream>>>(
      hb, csr_src, row_ptr, dinv, b2, nullptr, out, N);
}